// Round 10
// baseline (149.591 us; speedup 1.0000x reference)
//
#include <hip/hip_runtime.h>
#include <math.h>

// StructLoss: sqrt(mean(|grads4(outputs - labels)|) + 1e-16)
// grads4 linear -> compute on d = outputs - labels.
// [B=16, C=6, H=512, W=512] fp32; mean over B*4C*H*W.
//
// R2's proven same-iteration skeleton (load -> convert -> stencil inside one
// body; nothing lives across iterations except converted Rows) at STRIP=4
// for 2x the wave count: 12288 waves / 3072 blocks (12 blocks/CU requested)
// to hide L3-hit latency with TLP, since register pipelining is sunk by the
// compiler (R3/R6/R7/R9) and no pipe is near saturation (VALU ~10%, HBM
// ~20%). Branchless edges: clamped row address + 0/1 mask; column edges via
// lane shuffles. XCD-chunked block swizzle keeps halo-sharing neighbor
// strips in one XCD's L2. Fused deterministic last-block mean+sqrt tail.

#define NTHREADS 256
#define STRIP 4
#define WV 512
#define HT 512
#define PLANES 96
#define CHUNKS_PER_PLANE (HT / STRIP)                    // 128
#define TOTAL_WAVES (PLANES * CHUNKS_PER_PLANE)          // 12288
#define NBLOCKS (TOTAL_WAVES / (NTHREADS / 64))          // 3072
#define NXCD 8

struct Raw { float4 o0, o1, l0, l1; };
struct Row { float d[8]; float eL, eR; };

__device__ __forceinline__ Raw load_row(const float* __restrict__ ob,
                                        const float* __restrict__ lb, int r) {
    const int gr = min(max(r, 0), HT - 1);       // clamp: address always valid
    const size_t off = (size_t)gr * WV;
    Raw w;
    w.o0 = *reinterpret_cast<const float4*>(ob + off);
    w.o1 = *reinterpret_cast<const float4*>(ob + off + 4);
    w.l0 = *reinterpret_cast<const float4*>(lb + off);
    w.l1 = *reinterpret_cast<const float4*>(lb + off + 4);
    return w;
}

__device__ __forceinline__ Row convert(const Raw& w, int lane, float m) {
    Row row;
    row.d[0] = m * (w.o0.x - w.l0.x); row.d[1] = m * (w.o0.y - w.l0.y);
    row.d[2] = m * (w.o0.z - w.l0.z); row.d[3] = m * (w.o0.w - w.l0.w);
    row.d[4] = m * (w.o1.x - w.l1.x); row.d[5] = m * (w.o1.y - w.l1.y);
    row.d[6] = m * (w.o1.z - w.l1.z); row.d[7] = m * (w.o1.w - w.l1.w);
    const float up = __shfl_up(row.d[7], 1, 64);
    const float dn = __shfl_down(row.d[0], 1, 64);
    row.eL = (lane == 0)  ? 0.f : up;    // col 8l-1 (image zero-pad)
    row.eR = (lane == 63) ? 0.f : dn;    // col 8l+8 (image zero-pad)
    return row;
}

__device__ __forceinline__ float stencil(const Row& rp, const Row& rc,
                                         const Row& rn) {
    float a = 0.f;
    #pragma unroll
    for (int k = 0; k < 8; ++k) {
        const float cL = (k > 0) ? rc.d[k - 1] : rc.eL;
        const float cR = (k < 7) ? rc.d[k + 1] : rc.eR;
        const float pL = (k > 0) ? rp.d[k - 1] : rp.eL;
        const float pR = (k < 7) ? rp.d[k + 1] : rp.eR;
        const float nL = (k > 0) ? rn.d[k - 1] : rn.eL;
        const float nR = (k < 7) ? rn.d[k + 1] : rn.eR;

        const float gy = rp.d[k] - rn.d[k];   // x[i-1,j]   - x[i+1,j]
        const float gx = cL - cR;             // x[i,j-1]   - x[i,j+1]
        const float gD = pL - nR;             // x[i-1,j-1] - x[i+1,j+1]
        const float gd = pR - nL;             // x[i-1,j+1] - x[i+1,j-1]
        a += fabsf(gy) + fabsf(gx) + fabsf(gD) + fabsf(gd);
    }
    return a;
}

__global__ __launch_bounds__(NTHREADS) void struct_loss(
        const float* __restrict__ out_p, const float* __restrict__ lab_p,
        float* __restrict__ partials, unsigned* __restrict__ counter,
        float* __restrict__ out, double inv_count) {
    const int tid  = threadIdx.x;
    const int lane = tid & 63;
    const int wid  = tid >> 6;

    // XCD-chunked swizzle (3072 % 8 == 0 -> bijective): each XCD gets a
    // contiguous run of 384 work-blocks so neighbor strips (shared halo
    // rows) hit the same per-XCD L2.
    const int wb   = (blockIdx.x & (NXCD - 1)) * (NBLOCKS / NXCD)
                   + (blockIdx.x >> 3);
    const int gw   = wb * (NTHREADS / 64) + wid;           // 0..12287
    const int plane = gw >> 7;                             // / CHUNKS_PER_PLANE
    const int r0    = (gw & (CHUNKS_PER_PLANE - 1)) * STRIP;

    const size_t base = (size_t)plane * (HT * WV) + lane * 8;
    const float* ob = out_p + base;
    const float* lb = lab_p + base;

    float acc = 0.f;

    // Prologue: rows r0-1, r0.
    Raw A = load_row(ob, lb, r0 - 1);
    Raw B = load_row(ob, lb, r0);
    Row rp = convert(A, lane, (r0 > 0) ? 1.f : 0.f);
    Row rc = convert(B, lane, 1.f);

    #pragma unroll
    for (int rr = 0; rr < STRIP; ++rr) {
        // Load + convert + consume all in the same body: cannot be sunk.
        Raw C = load_row(ob, lb, r0 + rr + 1);
        const float m = (r0 + rr + 1 < HT) ? 1.f : 0.f;
        Row rn = convert(C, lane, m);
        acc += stencil(rp, rc, rn);
        rp = rc;
        rc = rn;
    }

    // ---- wave + block reduction ----
    #pragma unroll
    for (int off = 32; off > 0; off >>= 1)
        acc += __shfl_down(acc, off, 64);

    __shared__ float smem[NTHREADS / 64];
    if (lane == 0) smem[wid] = acc;
    __syncthreads();

    __shared__ bool amLast;
    if (tid == 0) {
        float s = 0.f;
        #pragma unroll
        for (int w = 0; w < NTHREADS / 64; ++w) s += smem[w];
        partials[blockIdx.x] = s;
        __threadfence();                          // publish partial
        const unsigned old = atomicAdd(counter, 1u);
        amLast = (old == (unsigned)(NBLOCKS - 1));
    }
    __syncthreads();

    if (amLast) {
        __threadfence();                          // see all partials
        double s = 0.0;
        for (int i = tid; i < NBLOCKS; i += NTHREADS)  // fixed order: determ.
            s += (double)partials[i];
        #pragma unroll
        for (int off = 32; off > 0; off >>= 1)
            s += __shfl_down(s, off, 64);
        __shared__ double dsm[NTHREADS / 64];
        if (lane == 0) dsm[wid] = s;
        __syncthreads();
        if (tid == 0) {
            double t = 0.0;
            #pragma unroll
            for (int w = 0; w < NTHREADS / 64; ++w) t += dsm[w];
            out[0] = (float)sqrt(t * inv_count + 1e-16);
        }
    }
}

extern "C" void kernel_launch(void* const* d_in, const int* in_sizes, int n_in,
                              void* d_out, int out_size, void* d_ws, size_t ws_size,
                              hipStream_t stream) {
    const float* outputs = (const float*)d_in[0];
    const float* labels  = (const float*)d_in[1];
    float* out = (float*)d_out;

    unsigned* counter = (unsigned*)d_ws;            // u32 at offset 0
    float* partials   = (float*)d_ws + 16;          // 3072 floats at 64 B off

    const double inv_count = 1.0 / (16.0 * 24.0 * 512.0 * 512.0);

    hipMemsetAsync(counter, 0, sizeof(unsigned), stream);
    struct_loss<<<NBLOCKS, NTHREADS, 0, stream>>>(outputs, labels, partials,
                                                  counter, out, inv_count);
}

// Round 11
// 63.188 us; speedup vs baseline: 2.3674x; 2.3674x over previous
//
#include <hip/hip_runtime.h>
#include <math.h>

// StructLoss: sqrt(mean(|grads4(outputs - labels)|) + 1e-16)
// grads4 linear -> compute on d = outputs - labels.
// [B=16, C=6, H=512, W=512] fp32; mean over B*4C*H*W.
//
// R6 structure (best so far, 40.2 us) + fused last-block tail (single
// launch). Persistent pipeline: 768 blocks (3/CU exactly), each owns 4
// consecutive 16-row strips. While computing strip t from LDS, strip t+1's
// raw halo tile (18 rows x 2 arrays) is register-staged via unconditional
// clamped float4 loads. Subtract + zero-pad mask at ds_write. Compute:
// per-wave 4-row rolling window, shfl column edges. Tail: last-block
// atomic counter, fixed-order double reduction (deterministic).

#define NTHREADS 256
#define TROWS 16
#define SROWS (TROWS + 2)                        // 18 staged rows
#define WV 512
#define HT 512
#define PLANES 96
#define STRIPS_PER_PLANE (HT / TROWS)            // 32
#define TOTAL_STRIPS (PLANES * STRIPS_PER_PLANE) // 3072
#define SPB 4                                    // strips per block
#define NBLOCKS (TOTAL_STRIPS / SPB)             // 768 = 3 blocks/CU exactly
#define LDK 9                                    // float4 per thread per array

struct Row { float d[8]; float eL, eR; };

__device__ __forceinline__ Row lds_row(const float* __restrict__ sd,
                                       int sr, int lane) {
    Row row;
    const float4 a = *reinterpret_cast<const float4*>(sd + sr * WV + lane * 8);
    const float4 b = *reinterpret_cast<const float4*>(sd + sr * WV + lane * 8 + 4);
    row.d[0] = a.x; row.d[1] = a.y; row.d[2] = a.z; row.d[3] = a.w;
    row.d[4] = b.x; row.d[5] = b.y; row.d[6] = b.z; row.d[7] = b.w;
    const float up = __shfl_up(row.d[7], 1, 64);
    const float dn = __shfl_down(row.d[0], 1, 64);
    row.eL = (lane == 0)  ? 0.f : up;   // col 8l-1 (image zero-pad)
    row.eR = (lane == 63) ? 0.f : dn;   // col 8l+8 (image zero-pad)
    return row;
}

__device__ __forceinline__ void issue_loads(const float* __restrict__ out_p,
                                            const float* __restrict__ lab_p,
                                            int s, int tid,
                                            float4 (&ov)[LDK], float4 (&lv)[LDK]) {
    const int plane = s >> 5;                    // / STRIPS_PER_PLANE
    const int row0  = (s & 31) * TROWS;
    const size_t pbase = (size_t)plane * (HT * WV);
    #pragma unroll
    for (int k = 0; k < LDK; ++k) {
        const int p  = tid + NTHREADS * k;       // float4 slot 0..2303
        const int r  = p >> 7;                   // staged row 0..17
        const int c4 = p & 127;
        const int gr = min(max(row0 + r - 1, 0), HT - 1);  // clamp: always valid
        const size_t goff = pbase + (size_t)gr * WV + c4 * 4;
        ov[k] = *reinterpret_cast<const float4*>(out_p + goff);
        lv[k] = *reinterpret_cast<const float4*>(lab_p + goff);
    }
}

__device__ __forceinline__ void write_tile(float* __restrict__ sd, int s, int tid,
                                           const float4 (&ov)[LDK],
                                           const float4 (&lv)[LDK]) {
    const int row0 = (s & 31) * TROWS;
    #pragma unroll
    for (int k = 0; k < LDK; ++k) {
        const int p = tid + NTHREADS * k;
        const int r = p >> 7;
        const int gr = row0 + r - 1;
        const float m = ((unsigned)gr < (unsigned)HT) ? 1.f : 0.f;  // zero-pad halo
        float4 d;
        d.x = m * (ov[k].x - lv[k].x);
        d.y = m * (ov[k].y - lv[k].y);
        d.z = m * (ov[k].z - lv[k].z);
        d.w = m * (ov[k].w - lv[k].w);
        *reinterpret_cast<float4*>(sd + (size_t)p * 4) = d;
    }
}

__device__ __forceinline__ float compute_tile(const float* __restrict__ sd,
                                              int wid, int lane) {
    float acc = 0.f;
    const int sr0 = wid * 4;                     // wave owns tile rows 4w..4w+3
    Row rp = lds_row(sd, sr0,     lane);
    Row rc = lds_row(sd, sr0 + 1, lane);
    #pragma unroll
    for (int rr = 0; rr < 4; ++rr) {
        Row rn = lds_row(sd, sr0 + 2 + rr, lane);
        #pragma unroll
        for (int k = 0; k < 8; ++k) {
            const float cL = (k > 0) ? rc.d[k - 1] : rc.eL;
            const float cR = (k < 7) ? rc.d[k + 1] : rc.eR;
            const float pL = (k > 0) ? rp.d[k - 1] : rp.eL;
            const float pR = (k < 7) ? rp.d[k + 1] : rp.eR;
            const float nL = (k > 0) ? rn.d[k - 1] : rn.eL;
            const float nR = (k < 7) ? rn.d[k + 1] : rn.eR;

            const float gy = rp.d[k] - rn.d[k];   // x[i-1,j]   - x[i+1,j]
            const float gx = cL - cR;             // x[i,j-1]   - x[i,j+1]
            const float gD = pL - nR;             // x[i-1,j-1] - x[i+1,j+1]
            const float gd = pR - nL;             // x[i-1,j+1] - x[i+1,j-1]
            acc += fabsf(gy) + fabsf(gx) + fabsf(gD) + fabsf(gd);
        }
        rp = rc;
        rc = rn;
    }
    return acc;
}

__global__ __launch_bounds__(NTHREADS) void struct_loss(
        const float* __restrict__ out_p, const float* __restrict__ lab_p,
        float* __restrict__ partials, unsigned* __restrict__ counter,
        float* __restrict__ out, double inv_count) {
    __shared__ float sd[SROWS * WV];             // 36,864 B

    const int tid  = threadIdx.x;
    const int wid  = tid >> 6;
    const int lane = tid & 63;
    const int s0   = blockIdx.x * SPB;           // 4 consecutive strips

    float acc = 0.f;
    float4 ov[LDK], lv[LDK];

    // Prologue: stage strip 0 (latency exposed once per block).
    issue_loads(out_p, lab_p, s0, tid, ov, lv);
    __builtin_amdgcn_sched_barrier(0);
    write_tile(sd, s0, tid, ov, lv);
    __syncthreads();

    #pragma unroll
    for (int t = 0; t < SPB; ++t) {
        // Issue next strip's loads BEFORE computing current.
        if (t + 1 < SPB) {
            issue_loads(out_p, lab_p, s0 + t + 1, tid, ov, lv);
            __builtin_amdgcn_sched_barrier(0);
        }
        acc += compute_tile(sd, wid, lane);
        __syncthreads();                         // all waves done reading sd
        if (t + 1 < SPB) {
            write_tile(sd, s0 + t + 1, tid, ov, lv);
            __syncthreads();                     // writes visible
        }
    }

    // ---- wave + block reduction ----
    #pragma unroll
    for (int off = 32; off > 0; off >>= 1)
        acc += __shfl_down(acc, off, 64);

    __shared__ float smem[NTHREADS / 64];
    if (lane == 0) smem[wid] = acc;
    __syncthreads();

    __shared__ bool amLast;
    if (tid == 0) {
        float s = 0.f;
        #pragma unroll
        for (int w = 0; w < NTHREADS / 64; ++w) s += smem[w];
        partials[blockIdx.x] = s;
        __threadfence();                          // publish partial
        const unsigned old = atomicAdd(counter, 1u);
        amLast = (old == (unsigned)(NBLOCKS - 1));
    }
    __syncthreads();

    if (amLast) {
        __threadfence();                          // see all partials
        double s = 0.0;
        for (int i = tid; i < NBLOCKS; i += NTHREADS)  // fixed order: determ.
            s += (double)partials[i];
        #pragma unroll
        for (int off = 32; off > 0; off >>= 1)
            s += __shfl_down(s, off, 64);
        __shared__ double dsm[NTHREADS / 64];
        if (lane == 0) dsm[wid] = s;
        __syncthreads();
        if (tid == 0) {
            double t = 0.0;
            #pragma unroll
            for (int w = 0; w < NTHREADS / 64; ++w) t += dsm[w];
            out[0] = (float)sqrt(t * inv_count + 1e-16);
        }
    }
}

extern "C" void kernel_launch(void* const* d_in, const int* in_sizes, int n_in,
                              void* d_out, int out_size, void* d_ws, size_t ws_size,
                              hipStream_t stream) {
    const float* outputs = (const float*)d_in[0];
    const float* labels  = (const float*)d_in[1];
    float* out = (float*)d_out;

    unsigned* counter = (unsigned*)d_ws;            // u32 at offset 0
    float* partials   = (float*)d_ws + 16;          // 768 floats at 64 B offset

    const double inv_count = 1.0 / (16.0 * 24.0 * 512.0 * 512.0);

    hipMemsetAsync(counter, 0, sizeof(unsigned), stream);
    struct_loss<<<NBLOCKS, NTHREADS, 0, stream>>>(outputs, labels, partials,
                                                  counter, out, inv_count);
}

// Round 12
// 37.970 us; speedup vs baseline: 3.9397x; 1.6642x over previous
//
#include <hip/hip_runtime.h>
#include <math.h>

// StructLoss: sqrt(mean(|grads4(outputs - labels)|) + 1e-16)
// grads4 linear -> compute on d = outputs - labels.
// [B=16, C=6, H=512, W=512] fp32; mean over B*4C*H*W.
//
// R6 structure (best, 40.2 us) + circular-slot halo reuse: block owns a
// 64-row band (4 strips x 16 rows) of one plane; LDS is an 18-slot row
// ring (slot(g) = (g+1) mod 18) holding d = out - lab. Prologue stages 18
// rows; each later strip stages only 16 NEW rows (the 2 halo rows carry
// over) -> traffic 1.031x vs R6's 1.125x. Loads issued before compute,
// ds_writes after the read barrier (write set == slots being retired).
// Separate tiny final kernel (fused tail regressed 23 us in R11 via
// per-block device-fence L2 thrash).

#define NTHREADS 256
#define TROWS 16
#define SLOTS 18
#define WV 512
#define HT 512
#define PLANES 96
#define SPB 4                                     // strips per block
#define BAND (SPB * TROWS)                        // 64 rows per block
#define BLOCKS_PER_PLANE (HT / BAND)              // 8
#define NBLOCKS (PLANES * BLOCKS_PER_PLANE)       // 768 = 3 blocks/CU
#define LDK_PRO 9                                 // 18 rows: float4/thread
#define LDK 8                                     // 16 rows: float4/thread

struct Row { float d[8]; float eL, eR; };

__device__ __forceinline__ Row lds_row(const float* __restrict__ sd,
                                       int slot, int lane) {
    Row row;
    const float4 a = *reinterpret_cast<const float4*>(sd + slot * WV + lane * 8);
    const float4 b = *reinterpret_cast<const float4*>(sd + slot * WV + lane * 8 + 4);
    row.d[0] = a.x; row.d[1] = a.y; row.d[2] = a.z; row.d[3] = a.w;
    row.d[4] = b.x; row.d[5] = b.y; row.d[6] = b.z; row.d[7] = b.w;
    const float up = __shfl_up(row.d[7], 1, 64);
    const float dn = __shfl_down(row.d[0], 1, 64);
    row.eL = (lane == 0)  ? 0.f : up;   // col 8l-1 (image zero-pad)
    row.eR = (lane == 63) ? 0.f : dn;   // col 8l+8 (image zero-pad)
    return row;
}

__device__ __forceinline__ float stencil(const Row& rp, const Row& rc,
                                         const Row& rn) {
    float a = 0.f;
    #pragma unroll
    for (int k = 0; k < 8; ++k) {
        const float cL = (k > 0) ? rc.d[k - 1] : rc.eL;
        const float cR = (k < 7) ? rc.d[k + 1] : rc.eR;
        const float pL = (k > 0) ? rp.d[k - 1] : rp.eL;
        const float pR = (k < 7) ? rp.d[k + 1] : rp.eR;
        const float nL = (k > 0) ? rn.d[k - 1] : rn.eL;
        const float nR = (k < 7) ? rn.d[k + 1] : rn.eR;

        const float gy = rp.d[k] - rn.d[k];   // x[i-1,j]   - x[i+1,j]
        const float gx = cL - cR;             // x[i,j-1]   - x[i,j+1]
        const float gD = pL - nR;             // x[i-1,j-1] - x[i+1,j+1]
        const float gd = pR - nL;             // x[i-1,j+1] - x[i+1,j-1]
        a += fabsf(gy) + fabsf(gx) + fabsf(gD) + fabsf(gd);
    }
    return a;
}

__global__ __launch_bounds__(NTHREADS) void struct_loss_partial(
        const float* __restrict__ out_p, const float* __restrict__ lab_p,
        float* __restrict__ partials) {
    __shared__ float sd[SLOTS * WV];              // 36,864 B

    const int tid  = threadIdx.x;
    const int wid  = tid >> 6;
    const int lane = tid & 63;
    const int plane = blockIdx.x >> 3;            // / BLOCKS_PER_PLANE
    const int S0    = (blockIdx.x & (BLOCKS_PER_PLANE - 1)) * BAND;
    const int sbase = S0 % SLOTS;                 // slot of row S0-1
    const size_t pbase = (size_t)plane * (HT * WV);

    // ---- prologue: stage rows S0-1 .. S0+16 into slots (sbase+r)%18 ----
    {
        float4 ov[LDK_PRO], lv[LDK_PRO];
        #pragma unroll
        for (int k = 0; k < LDK_PRO; ++k) {
            const int p  = tid + NTHREADS * k;    // 0..2303
            const int r  = p >> 7;                // 0..17
            const int c4 = p & 127;
            const int g  = S0 - 1 + r;
            const int gc = max(g, 0);             // g <= 464 always
            const size_t goff = pbase + (size_t)gc * WV + c4 * 4;
            ov[k] = *reinterpret_cast<const float4*>(out_p + goff);
            lv[k] = *reinterpret_cast<const float4*>(lab_p + goff);
        }
        #pragma unroll
        for (int k = 0; k < LDK_PRO; ++k) {
            const int p  = tid + NTHREADS * k;
            const int r  = p >> 7;
            const int c4 = p & 127;
            const int g  = S0 - 1 + r;
            const float m = (g >= 0) ? 1.f : 0.f;
            int slot = sbase + r; if (slot >= SLOTS) slot -= SLOTS;
            float4 d;
            d.x = m * (ov[k].x - lv[k].x);
            d.y = m * (ov[k].y - lv[k].y);
            d.z = m * (ov[k].z - lv[k].z);
            d.w = m * (ov[k].w - lv[k].w);
            *reinterpret_cast<float4*>(sd + slot * WV + c4 * 4) = d;
        }
    }
    __syncthreads();

    float acc = 0.f;
    float4 ov[LDK], lv[LDK];

    #pragma unroll
    for (int t = 0; t < SPB; ++t) {
        const int R0 = S0 + t * TROWS;

        // Issue next strip's 16 NEW rows (R0+17 .. R0+32) before compute.
        if (t + 1 < SPB) {
            #pragma unroll
            for (int k = 0; k < LDK; ++k) {
                const int p  = tid + NTHREADS * k;   // 0..2047
                const int r  = p >> 7;               // 0..15
                const int c4 = p & 127;
                const int g  = R0 + 17 + r;
                const int gc = min(g, HT - 1);       // clamp: addr always valid
                const size_t goff = pbase + (size_t)gc * WV + c4 * 4;
                ov[k] = *reinterpret_cast<const float4*>(out_p + goff);
                lv[k] = *reinterpret_cast<const float4*>(lab_p + goff);
            }
            __builtin_amdgcn_sched_barrier(0);
        }

        // Compute strip rows R0+4*wid .. +3 (slots (sbase+16t+4wid+i)%18).
        {
            const int m0 = (sbase + 16 * t + 4 * wid) % SLOTS;
            int s_c = m0 + 1; if (s_c >= SLOTS) s_c -= SLOTS;
            Row rp = lds_row(sd, m0, lane);
            Row rc = lds_row(sd, s_c, lane);
            #pragma unroll
            for (int rr = 0; rr < 4; ++rr) {
                int s_n = m0 + 2 + rr; if (s_n >= SLOTS) s_n -= SLOTS;
                Row rn = lds_row(sd, s_n, lane);
                acc += stencil(rp, rc, rn);
                rp = rc;
                rc = rn;
            }
        }
        __syncthreads();                             // all reads done

        // Retire oldest 16 slots with the new rows.
        if (t + 1 < SPB) {
            #pragma unroll
            for (int k = 0; k < LDK; ++k) {
                const int p  = tid + NTHREADS * k;
                const int r  = p >> 7;
                const int c4 = p & 127;
                const int g  = R0 + 17 + r;
                const float m = (g < HT) ? 1.f : 0.f;  // zero-pad bottom
                int slot = (sbase + 16 * t + r) % SLOTS;
                float4 d;
                d.x = m * (ov[k].x - lv[k].x);
                d.y = m * (ov[k].y - lv[k].y);
                d.z = m * (ov[k].z - lv[k].z);
                d.w = m * (ov[k].w - lv[k].w);
                *reinterpret_cast<float4*>(sd + slot * WV + c4 * 4) = d;
            }
            __syncthreads();                         // writes visible
        }
    }

    // ---- wave + block reduction ----
    #pragma unroll
    for (int off = 32; off > 0; off >>= 1)
        acc += __shfl_down(acc, off, 64);

    __shared__ float smem[NTHREADS / 64];
    if (lane == 0) smem[wid] = acc;
    __syncthreads();
    if (tid == 0) {
        float s = 0.f;
        #pragma unroll
        for (int w = 0; w < NTHREADS / 64; ++w) s += smem[w];
        partials[blockIdx.x] = s;
    }
}

__global__ __launch_bounds__(256) void struct_loss_final(
        const float* __restrict__ partial, float* __restrict__ out,
        int nparts, double inv_count) {
    double acc = 0.0;
    for (int i = threadIdx.x; i < nparts; i += blockDim.x)
        acc += (double)partial[i];
    #pragma unroll
    for (int off = 32; off > 0; off >>= 1)
        acc += __shfl_down(acc, off, 64);
    __shared__ double smem[4];
    const int lane = threadIdx.x & 63;
    const int wid  = threadIdx.x >> 6;
    if (lane == 0) smem[wid] = acc;
    __syncthreads();
    if (threadIdx.x == 0) {
        double s = smem[0] + smem[1] + smem[2] + smem[3];
        out[0] = (float)sqrt(s * inv_count + 1e-16);
    }
}

extern "C" void kernel_launch(void* const* d_in, const int* in_sizes, int n_in,
                              void* d_out, int out_size, void* d_ws, size_t ws_size,
                              hipStream_t stream) {
    const float* outputs = (const float*)d_in[0];
    const float* labels  = (const float*)d_in[1];
    float* out = (float*)d_out;
    float* partials = (float*)d_ws;   // NBLOCKS floats

    const double inv_count = 1.0 / (16.0 * 24.0 * 512.0 * 512.0);

    struct_loss_partial<<<NBLOCKS, NTHREADS, 0, stream>>>(outputs, labels, partials);
    struct_loss_final<<<1, 256, 0, stream>>>(partials, out, NBLOCKS, inv_count);
}